// Round 6
// baseline (172.413 us; speedup 1.0000x reference)
//
#include <hip/hip_runtime.h>
#include <hip/hip_fp16.h>

// Problem constants (fixed by reference)
#define BB 8
#define NN 1024
#define HH 768
#define NHEAD 12
#define HD 64
#define NSEG 8192            // B*N
#define QKVN 2304            // 3*H
#define MAXDEG 64            // bucket capacity per segment (Poisson(16); P(>64) ~ 1e-18)

typedef unsigned short u16;
typedef __attribute__((ext_vector_type(8))) _Float16 f16x8;
typedef __attribute__((ext_vector_type(4))) float f32x4;
typedef __attribute__((ext_vector_type(4))) unsigned int u32x4;
typedef __attribute__((ext_vector_type(2))) unsigned int u32x2;

__device__ __forceinline__ u16 f2h(float f) {
  _Float16 h = (_Float16)f;
  return __builtin_bit_cast(u16, h);
}
__device__ __forceinline__ __half2 h2(unsigned int w) {
  return __builtin_bit_cast(__half2, w);
}

// ---------------- fused prep: cast X, transpose W, build CSR ----------------
#define CAST_BLKS (NSEG * HH / 4 / 256)     // 6144
#define TW_BLKS   ((QKVN / 32) * (HH / 32)) // 1728
#define BUILD_BLKS 512

__global__ void prep_kernel(const float* __restrict__ X, u16* __restrict__ Xb,
                            const float* __restrict__ Wq, const float* __restrict__ Wk,
                            const float* __restrict__ Wv, u16* __restrict__ Wt,
                            const int* __restrict__ EI, int* __restrict__ cursor,
                            int* __restrict__ tailrow, int E) {
  const int bid = blockIdx.x;
  if (bid < CAST_BLKS) {
    int i = bid * 256 + threadIdx.x;
    float4 f = ((const float4*)X)[i];
    ushort4 o;
    o.x = f2h(f.x); o.y = f2h(f.y); o.z = f2h(f.z); o.w = f2h(f.w);
    ((ushort4*)Xb)[i] = o;
  } else if (bid < CAST_BLKS + TW_BLKS) {
    __shared__ float tile[32][33];
    int t = bid - CAST_BLKS;
    int n0 = (t % (QKVN / 32)) * 32;
    int k0 = (t / (QKVN / 32)) * 32;
    const float* W = (n0 < HH) ? Wq : (n0 < 2 * HH ? Wk : Wv);
    int nb = n0 - (n0 < HH ? 0 : (n0 < 2 * HH ? HH : 2 * HH));
    int tx = threadIdx.x & 31, ty = threadIdx.x >> 5;   // (32, 8)
#pragma unroll
    for (int r = 0; r < 4; ++r)
      tile[ty + 8 * r][tx] = W[(k0 + ty + 8 * r) * HH + nb + tx];
    __syncthreads();
#pragma unroll
    for (int r = 0; r < 4; ++r)
      Wt[(n0 + ty + 8 * r) * HH + k0 + tx] = f2h(tile[tx][ty + 8 * r]);
  } else {
    int e = (bid - CAST_BLKS - TW_BLKS) * 256 + threadIdx.x;
    if (e >= E) return;
    int b = EI[e];
    int seg = b * NN + EI[E + e];
    int j = EI[2 * E + e];
    int pos = atomicAdd(&cursor[seg], 1);
    if (pos < MAXDEG) tailrow[seg * MAXDEG + pos] = b * NN + j;
  }
}

// ---------------- fused QKV GEMM: (8192x768) @ (768x2304), f16 MFMA ----------------
// R17: issue-ahead schedule on the fine-packing 576 grid.
//   Diagnosis across R12-R16: every schedule that does {ds_read; lgkmcnt(0);
//   MFMA} per phase exposes the ~120cy ds_read latency each phase (only 2
//   waves/SIMD, near-lockstep -> nothing covers it). Fix = m201's counted
//   lgkm pattern: issue ALL 16 frag reads (both K-halves) + all 6
//   global_load_lds, then lgkmcnt(8) -> MFMA(ks0) runs while the ks1 reads
//   land -> lgkmcnt(0) -> MFMA(ks1).
//   Geometry: BM=256 x BN=128, BK=64, 512 thr = 8 waves (4M x 2N of 64x64).
//   576 blocks pack as ~2.25 rounds of ~8-9us blocks (makespan bound ~20us,
//   beats the 288-grid's 2x12.4us despite the lower FLOP/LDS-byte ratio).
//   ONE barrier per K-tile (head, post-vmcnt(0)): stages into buf^1 begin
//   only after it, and any wave past it has finished reading buf^1 (program
//   order). vmcnt(0) at head is free: those loads were issued >=1200cy ago.
//   Swizzle: p = chunk ^ (row&7) on 16B chunks of 128B rows (R5: measured
//   0 conflicts). sched_barrier(0) after each lgkm wait (rule 18).
#define BM 256
#define BN 128
#define BKT 64
#define NKT (HH / BKT)      // 12

__global__ __launch_bounds__(512, 2) void gemm_kernel(const u16* __restrict__ Xb,
                                                      const u16* __restrict__ Wt,
                                                      u16* __restrict__ QKV) {
  __shared__ u16 As[2][BM * BKT];   // 2 x 32 KB
  __shared__ u16 Bs[2][BN * BKT];   // 2 x 16 KB   -> 96 KB total
  const int tid = threadIdx.x;
  const int wave = tid >> 6;
  const int lane = tid & 63;
  const int quad = lane >> 4;
  const int l15 = lane & 15;
  const int wm = (wave >> 1) * 64;   // 4 M-waves
  const int wn = (wave & 1) * 64;    // 2 N-waves

  // XCD-bijective map: 576 = 8 chunks x 72, m-major within chunk (A-panel
  // L2 reuse); tail blocks (bid 512..575) spread evenly over all 8 XCDs.
  const int bid = blockIdx.x;
  const int wgid = (bid & 7) * 72 + (bid >> 3);
  const int mt = wgid / 18;          // 0..31
  const int nt = wgid % 18;          // 0..17
  const int m0 = mt * BM;
  const int n0 = nt * BN;

  f32x4 acc[4][4] = {};

  // stage K-tile kt into buf kt&1. A: 2048 16B-chunks (4/thread);
  // B: 1024 (2/thread). LDS dest linear; global source pre-swizzled with the
  // involution lg = p ^ (r&7)  (store slot p holds logical chunk lg).
  auto stageA = [&](int kt) {
    const int buf = kt & 1;
#pragma unroll
    for (int ld = 0; ld < 4; ++ld) {
      const int c = ld * 512 + tid;          // 0..2047
      const int r = c >> 3;                  // 0..255
      const int p = c & 7;
      const int lg = p ^ (r & 7);
      const u16* g = Xb + (m0 + r) * HH + kt * BKT + lg * 8;
      u16* l = &As[buf][r * 64 + p * 8];
      __builtin_amdgcn_global_load_lds(
          (const __attribute__((address_space(1))) unsigned int*)(unsigned long long)g,
          (__attribute__((address_space(3))) unsigned int*)(unsigned long long)l, 16, 0, 0);
    }
  };
  auto stageB = [&](int kt) {
    const int buf = kt & 1;
#pragma unroll
    for (int ld = 0; ld < 2; ++ld) {
      const int c = ld * 512 + tid;          // 0..1023
      const int r = c >> 3;                  // 0..127
      const int p = c & 7;
      const int lg = p ^ (r & 7);
      const u16* g = Wt + (n0 + r) * HH + kt * BKT + lg * 8;
      u16* l = &Bs[buf][r * 64 + p * 8];
      __builtin_amdgcn_global_load_lds(
          (const __attribute__((address_space(1))) unsigned int*)(unsigned long long)g,
          (__attribute__((address_space(3))) unsigned int*)(unsigned long long)l, 16, 0, 0);
    }
  };

  // prologue
  stageA(0);
  stageB(0);

#pragma unroll 2
  for (int kt = 0; kt < NKT; ++kt) {
    const int buf = kt & 1;
    const bool pre = (kt + 1) < NKT;

    asm volatile("s_waitcnt vmcnt(0)" ::: "memory");   // buf's stages landed
    __builtin_amdgcn_s_barrier();                       // all waves' stages landed

    // issue ALL 16 frag reads (ks=0 first 8, ks=1 last 8), then staging
    f16x8 a0[4], b0[4], a1[4], b1[4];
#pragma unroll
    for (int mi = 0; mi < 4; ++mi) {
      const int rr = wm + mi * 16 + l15;
      a0[mi] = *(const f16x8*)(&As[buf][rr * 64 + ((quad ^ (rr & 7)) << 3)]);
    }
#pragma unroll
    for (int ni = 0; ni < 4; ++ni) {
      const int rn = wn + ni * 16 + l15;
      b0[ni] = *(const f16x8*)(&Bs[buf][rn * 64 + ((quad ^ (rn & 7)) << 3)]);
    }
#pragma unroll
    for (int mi = 0; mi < 4; ++mi) {
      const int rr = wm + mi * 16 + l15;
      a1[mi] = *(const f16x8*)(&As[buf][rr * 64 + (((4 + quad) ^ (rr & 7)) << 3)]);
    }
#pragma unroll
    for (int ni = 0; ni < 4; ++ni) {
      const int rn = wn + ni * 16 + l15;
      b1[ni] = *(const f16x8*)(&Bs[buf][rn * 64 + (((4 + quad) ^ (rn & 7)) << 3)]);
    }
    if (pre) { stageA(kt + 1); stageB(kt + 1); }   // into buf^1: safe post-barrier

    // first 8 ds_reads retired; ks=1 reads land under MFMA(ks0)
    asm volatile("s_waitcnt lgkmcnt(8)" ::: "memory");
    __builtin_amdgcn_sched_barrier(0);
    __builtin_amdgcn_s_setprio(1);
#pragma unroll
    for (int mi = 0; mi < 4; ++mi)
#pragma unroll
      for (int ni = 0; ni < 4; ++ni)
        acc[mi][ni] = __builtin_amdgcn_mfma_f32_16x16x32_f16(a0[mi], b0[ni], acc[mi][ni], 0, 0, 0);
    __builtin_amdgcn_s_setprio(0);

    asm volatile("s_waitcnt lgkmcnt(0)" ::: "memory");
    __builtin_amdgcn_sched_barrier(0);
    __builtin_amdgcn_s_setprio(1);
#pragma unroll
    for (int mi = 0; mi < 4; ++mi)
#pragma unroll
      for (int ni = 0; ni < 4; ++ni)
        acc[mi][ni] = __builtin_amdgcn_mfma_f32_16x16x32_f16(a1[mi], b1[ni], acc[mi][ni], 0, 0, 0);
    __builtin_amdgcn_s_setprio(0);
  }

  // epilogue: C/D layout col=lane&15, row=(lane>>4)*4+reg  [m89-verified]
#pragma unroll
  for (int mi = 0; mi < 4; ++mi)
#pragma unroll
    for (int ni = 0; ni < 4; ++ni) {
      const int col = n0 + wn + ni * 16 + l15;
#pragma unroll
      for (int r = 0; r < 4; ++r) {
        const int row = m0 + wm + mi * 16 + quad * 4 + r;
        QKV[row * QKVN + col] = f2h(acc[mi][ni][r]);
      }
    }
}

// ---------------- attention: FOUR waves per segment, LDS merge ----------------
// (unchanged)
__global__ __launch_bounds__(256) void attn_kernel(const u16* __restrict__ QKV,
                                                   const int* __restrict__ tailrow,
                                                   const int* __restrict__ cursor,
                                                   float* __restrict__ out) {
  __shared__ float sm[3 * 16 * 64];   // 12 KB: partial states from waves 1..3
  const int wv = threadIdx.x >> 6;    // 0..3 = edge-stripe
  const int lane = threadIdx.x & 63;
  const int seg = (blockIdx.x & 7) * (NSEG / 8) + (blockIdx.x >> 3);  // XCD affinity
  const int base = seg * MAXDEG;
  int cnt = cursor[seg];
  if (cnt > MAXDEG) cnt = MAXDEG;
  const int myn = (cnt > wv) ? ((cnt - wv + 3) >> 2) : 0;   // edges at wv, wv+4, ...

  int myidx = (lane < cnt) ? tailrow[base + lane] : 0;

  const u16* qrow = QKV + seg * QKVN;
  __half2 q1[4], q2[2];
  {
    u32x4 qa = *(const u32x4*)(qrow + lane * 8);
    u32x2 qb = *(const u32x2*)(qrow + 512 + lane * 4);
    const __half2 sc = __float2half2_rn(0.125f);
#pragma unroll
    for (int i = 0; i < 4; ++i) q1[i] = __hmul2(h2(qa[i]), sc);
    q2[0] = __hmul2(h2(qb[0]), sc);
    q2[1] = __hmul2(h2(qb[1]), sc);
  }

  float m1 = -__builtin_inff(), l1 = 0.f;
  float m2 = -__builtin_inff(), l2 = 0.f;
  __half2 o1[4] = {}, o2[2] = {};

  auto loadkv = [&](int row, u32x4& k1, u32x2& k2, u32x4& v1, u32x2& v2) {
    const u16* kp = QKV + row * QKVN + HH;
    k1 = *(const u32x4*)(kp + lane * 8);
    k2 = *(const u32x2*)(kp + 512 + lane * 4);
    v1 = *(const u32x4*)(kp + HH + lane * 8);
    v2 = *(const u32x2*)(kp + HH + 512 + lane * 4);
  };

  auto process = [&](u32x4 k1, u32x2 k2, u32x4 v1, u32x2 v2) {
    __half2 a1 = __hmul2(q1[0], h2(k1[0]));
    a1 = __hfma2(q1[1], h2(k1[1]), a1);
    a1 = __hfma2(q1[2], h2(k1[2]), a1);
    a1 = __hfma2(q1[3], h2(k1[3]), a1);
    float s1 = __low2float(a1) + __high2float(a1);
    s1 += __shfl_xor(s1, 1, 64);
    s1 += __shfl_xor(s1, 2, 64);
    s1 += __shfl_xor(s1, 4, 64);
    __half2 a2 = __hmul2(q2[0], h2(k2[0]));
    a2 = __hfma2(q2[1], h2(k2[1]), a2);
    float s2 = __low2float(a2) + __high2float(a2);
    s2 += __shfl_xor(s2, 1, 64);
    s2 += __shfl_xor(s2, 2, 64);
    s2 += __shfl_xor(s2, 4, 64);
    s2 += __shfl_xor(s2, 8, 64);
    {
      float mn = fmaxf(m1, s1);
      float al = __expf(m1 - mn);
      float ex = __expf(s1 - mn);
      l1 = l1 * al + ex;
      __half2 ah = __float2half2_rn(al), eh = __float2half2_rn(ex);
#pragma unroll
      for (int i = 0; i < 4; ++i)
        o1[i] = __hfma2(o1[i], ah, __hmul2(h2(v1[i]), eh));
      m1 = mn;
    }
    {
      float mn = fmaxf(m2, s2);
      float al = __expf(m2 - mn);
      float ex = __expf(s2 - mn);
      l2 = l2 * al + ex;
      __half2 ah = __float2half2_rn(al), eh = __float2half2_rn(ex);
      o2[0] = __hfma2(o2[0], ah, __hmul2(h2(v2[0]), eh));
      o2[1] = __hfma2(o2[1], ah, __hmul2(h2(v2[1]), eh));
      m2 = mn;
    }
  };

  if (myn > 0) {
    u32x4 k1c, v1c, k1n, v1n, k1n2, v1n2;
    u32x2 k2c, v2c, k2n, v2n, k2n2, v2n2;
    loadkv(__shfl(myidx, wv, 64), k1c, k2c, v1c, v2c);
    if (myn > 1) loadkv(__shfl(myidx, wv + 4, 64), k1n, k2n, v1n, v2n);
    for (int t = 0; t < myn; ++t) {
      if (t + 2 < myn)
        loadkv(__shfl(myidx, wv + 4 * (t + 2), 64), k1n2, k2n2, v1n2, v2n2);
      process(k1c, k2c, v1c, v2c);
      k1c = k1n; k2c = k2n; v1c = v1n; v2c = v2n;
      k1n = k1n2; k2n = k2n2; v1n = v1n2; v2n = v2n2;
    }
  }

  float of1[8], of2[4];
#pragma unroll
  for (int i = 0; i < 4; ++i) {
    of1[2 * i] = __low2float(o1[i]);
    of1[2 * i + 1] = __high2float(o1[i]);
  }
#pragma unroll
  for (int i = 0; i < 2; ++i) {
    of2[2 * i] = __low2float(o2[i]);
    of2[2 * i + 1] = __high2float(o2[i]);
  }

  if (wv > 0) {
    float* sb = sm + (wv - 1) * 1024;
    sb[0 * 64 + lane] = m1;  sb[1 * 64 + lane] = l1;
    sb[2 * 64 + lane] = m2;  sb[3 * 64 + lane] = l2;
#pragma unroll
    for (int i = 0; i < 8; ++i) sb[(4 + i) * 64 + lane] = of1[i];
#pragma unroll
    for (int i = 0; i < 4; ++i) sb[(12 + i) * 64 + lane] = of2[i];
  }
  __syncthreads();
  if (wv == 0) {
    float mn1 = fmaxf(m1, -1e30f), mn2 = fmaxf(m2, -1e30f);
#pragma unroll
    for (int j = 0; j < 3; ++j) {
      mn1 = fmaxf(mn1, sm[j * 1024 + 0 * 64 + lane]);
      mn2 = fmaxf(mn2, sm[j * 1024 + 2 * 64 + lane]);
    }
    float res1[8], res2[4];
    {
      float a0 = __expf(m1 - mn1);
      float l = l1 * a0;
#pragma unroll
      for (int i = 0; i < 8; ++i) res1[i] = of1[i] * a0;
#pragma unroll
      for (int j = 0; j < 3; ++j) {
        const float* sb = sm + j * 1024;
        float aj = __expf(sb[0 * 64 + lane] - mn1);
        l += sb[1 * 64 + lane] * aj;
#pragma unroll
        for (int i = 0; i < 8; ++i) res1[i] += sb[(4 + i) * 64 + lane] * aj;
      }
      float inv = 1.f / fmaxf(l, 1e-9f);
#pragma unroll
      for (int i = 0; i < 8; ++i) res1[i] *= inv;
    }
    {
      float a0 = __expf(m2 - mn2);
      float l = l2 * a0;
#pragma unroll
      for (int i = 0; i < 4; ++i) res2[i] = of2[i] * a0;
#pragma unroll
      for (int j = 0; j < 3; ++j) {
        const float* sb = sm + j * 1024;
        float aj = __expf(sb[2 * 64 + lane] - mn2);
        l += sb[3 * 64 + lane] * aj;
#pragma unroll
        for (int i = 0; i < 4; ++i) res2[i] += sb[(12 + i) * 64 + lane] * aj;
      }
      float inv = 1.f / fmaxf(l, 1e-9f);
#pragma unroll
      for (int i = 0; i < 4; ++i) res2[i] *= inv;
    }

    float* op = out + seg * HH;
    float4 r0 = {res1[0], res1[1], res1[2], res1[3]};
    float4 r1 = {res1[4], res1[5], res1[6], res1[7]};
    float4 r2 = {res2[0], res2[1], res2[2], res2[3]};
    ((float4*)(op + lane * 8))[0] = r0;
    ((float4*)(op + lane * 8))[1] = r1;
    *(float4*)(op + 512 + lane * 4) = r2;
  }
}

// ---------------- launch ----------------
extern "C" void kernel_launch(void* const* d_in, const int* in_sizes, int n_in,
                              void* d_out, int out_size, void* d_ws, size_t ws_size,
                              hipStream_t stream) {
  const float* X  = (const float*)d_in[0];
  const int*   EI = (const int*)d_in[1];
  const float* Wq = (const float*)d_in[2];
  const float* Wk = (const float*)d_in[3];
  const float* Wv = (const float*)d_in[4];
  float* out = (float*)d_out;
  const int E = in_sizes[1] / 4;

  // workspace layout (~56 MB)
  char* ws = (char*)d_ws;
  int* cursor  = (int*)(ws);                 // 32 KB
  int* tailrow = (int*)(ws + 32768);         // NSEG*64*4 = 2 MB
  u16* Xb      = (u16*)(ws + 2129920);       // 8192*768*2  = 12.6 MB  (f16)
  u16* Wt      = (u16*)(ws + 14712832);      // 2304*768*2  = 3.5 MB   (f16)
  u16* QKV     = (u16*)(ws + 18251776);      // 8192*2304*2 = 37.7 MB  (f16)

  hipMemsetAsync(cursor, 0, NSEG * 4, stream);
  prep_kernel<<<CAST_BLKS + TW_BLKS + BUILD_BLKS, 256, 0, stream>>>(
      X, Xb, Wq, Wk, Wv, Wt, EI, cursor, tailrow, E);
  gemm_kernel<<<(NSEG / BM) * (QKVN / BN), 512, 0, stream>>>(Xb, Wt, QKV);
  attn_kernel<<<NSEG, 256, 0, stream>>>(QKV, tailrow, cursor, out);
}